// Round 2
// baseline (4819.169 us; speedup 1.0000x reference)
//
#include <hip/hip_runtime.h>

#define NS_ 26
#define NCLS_ 97

typedef short bf16x8 __attribute__((ext_vector_type(8)));
typedef float f32x4 __attribute__((ext_vector_type(4)));

__device__ __forceinline__ unsigned short f2bf(float f) {
  union { float f; unsigned u; } v; v.f = f;
  unsigned r = v.u + 0x7fffu + ((v.u >> 16) & 1u);
  return (unsigned short)(r >> 16);
}
__device__ __forceinline__ float bf2f(unsigned short h) {
  union { unsigned u; float f; } v; v.u = ((unsigned)h) << 16;
  return v.f;
}
__device__ __forceinline__ float sigm_f(float x) { return 1.f / (1.f + __expf(-x)); }
__device__ __forceinline__ float tanh_f(float x) { return 1.f - 2.f / (1.f + __expf(2.f * x)); }

__device__ __forceinline__ void gl_lds16(const void* g, void* l) {
  __builtin_amdgcn_global_load_lds(
      (const __attribute__((address_space(1))) unsigned int*)g,
      (__attribute__((address_space(3))) unsigned int*)l, 16, 0, 0);
}

// ============ tiled 128x128 GEMM, BK=64, swizzled LDS, global_load_lds ============
// out[M,N] = A[M,K] @ B[N,K]^T (+bias). M%128==0, K%64==0, B has >= gridDim.x*128 rows.
template <bool OUTF>
__global__ __launch_bounds__(256) void gemm_tiled_k(
    const unsigned short* __restrict__ Ag, const unsigned short* __restrict__ Bg,
    const float* __restrict__ bias, float* __restrict__ outF,
    unsigned short* __restrict__ outB, int K, long ldo, int Nvalid) {
  __shared__ unsigned short As[128 * 64];
  __shared__ unsigned short Bs[128 * 64];
  const int tid = threadIdx.x;
  const int w = tid >> 6, l = tid & 63;
  const int l15 = l & 15, lq = l >> 4;
  const int wm = w >> 1, wn = w & 1;
  const long rowBase = (long)blockIdx.y * 128;
  const long colBase = (long)blockIdx.x * 128;
  const int lrow = l >> 3, ps_st = l & 7;
  f32x4 acc[4][4] = {};
  for (int kt = 0; kt < K; kt += 64) {
#pragma unroll
    for (int i = 0; i < 4; ++i) {
      const int row = i * 32 + w * 8 + lrow;
      const int ls = ps_st ^ (row & 7);
      gl_lds16(Ag + (rowBase + row) * K + kt + ls * 8, As + i * 2048 + w * 512);
      gl_lds16(Bg + (colBase + row) * K + kt + ls * 8, Bs + i * 2048 + w * 512);
    }
    __syncthreads();
#pragma unroll
    for (int kh = 0; kh < 2; ++kh) {
      bf16x8 af[4], bfr[4];
#pragma unroll
      for (int mi = 0; mi < 4; ++mi) {
        const int row = wm * 64 + mi * 16 + l15;
        const int ps = (kh * 4 + lq) ^ (row & 7);
        af[mi] = *(const bf16x8*)(As + row * 64 + ps * 8);
      }
#pragma unroll
      for (int ni = 0; ni < 4; ++ni) {
        const int row = wn * 64 + ni * 16 + l15;
        const int ps = (kh * 4 + lq) ^ (row & 7);
        bfr[ni] = *(const bf16x8*)(Bs + row * 64 + ps * 8);
      }
#pragma unroll
      for (int mi = 0; mi < 4; ++mi)
#pragma unroll
        for (int ni = 0; ni < 4; ++ni)
          acc[mi][ni] = __builtin_amdgcn_mfma_f32_16x16x32_bf16(af[mi], bfr[ni], acc[mi][ni], 0, 0, 0);
    }
    __syncthreads();
  }
#pragma unroll
  for (int mi = 0; mi < 4; ++mi)
#pragma unroll
    for (int ni = 0; ni < 4; ++ni) {
      const long gcol = colBase + wn * 64 + ni * 16 + l15;
      if (gcol >= Nvalid) continue;
      const float bv = OUTF ? (bias ? bias[gcol] : 0.f) : 0.f;
#pragma unroll
      for (int r = 0; r < 4; ++r) {
        const long grow = rowBase + wm * 64 + mi * 16 + lq * 4 + r;
        const float v = acc[mi][ni][r] + bv;
        if (OUTF) outF[grow * ldo + gcol] = v;
        else      outB[grow * ldo + gcol] = f2bf(v);
      }
    }
}

// ============ small generic GEMM (64x64 tile, direct-from-L2) — used for hp ============
__global__ void gemm_hp_k(const unsigned short* __restrict__ A0,
                          const unsigned short* __restrict__ W,
                          const float* __restrict__ bias, float* __restrict__ outF) {
  const int tid = threadIdx.x;
  const int w = tid >> 6, l = tid & 63;
  const int l15 = l & 15, lq = l >> 4;
  const long mrow = (long)blockIdx.y * 64 + w * 16 + l15;
  const int nbase = blockIdx.x * 64;
  f32x4 acc[4] = {};
  for (int kt = 0; kt < 512; kt += 32) {
    const int k = kt + lq * 8;
    const bf16x8 a = *(const bf16x8*)(A0 + mrow * 512 + k);
#pragma unroll
    for (int nb = 0; nb < 4; ++nb) {
      const bf16x8 b = *(const bf16x8*)(W + (long)(nbase + nb * 16 + l15) * 512 + k);
      acc[nb] = __builtin_amdgcn_mfma_f32_16x16x32_bf16(a, b, acc[nb], 0, 0, 0);
    }
  }
#pragma unroll
  for (int nb = 0; nb < 4; ++nb) {
    const int colg = nbase + nb * 16 + l15;
    const float bv = bias[colg];
#pragma unroll
    for (int r = 0; r < 4; ++r) {
      const long rowg = (long)blockIdx.y * 64 + w * 16 + lq * 4 + r;
      outF[rowg * 512 + colg] = acc[nb][r] + bv;
    }
  }
}

// ============ attention step: e -> softmax -> context ============
__global__ __launch_bounds__(512) void attn_step_k(
    const unsigned short* __restrict__ Hproj, const unsigned short* __restrict__ bH,
    const float* __restrict__ hp, const float* __restrict__ w_score,
    float* __restrict__ attn_map, unsigned short* __restrict__ ctx, int s) {
  const int b = blockIdx.x, tid = threadIdx.x;
  __shared__ float hp_s[512], ws_s[512], e_s[64], csum[512];
  hp_s[tid] = hp[(long)b * 512 + tid];
  ws_s[tid] = w_score[tid];
  __syncthreads();
  const int w = tid >> 6, l = tid & 63;
  const unsigned short* Hrow = Hproj + ((long)b * 64 + w * 8) * 512 + l * 8;
#pragma unroll
  for (int tt = 0; tt < 8; ++tt) {
    const bf16x8 hv = *(const bf16x8*)(Hrow + tt * 512);
    float acc = 0.f;
#pragma unroll
    for (int j = 0; j < 8; ++j) {
      const int h = l * 8 + j;
      acc += tanh_f(bf2f((unsigned short)hv[j]) + hp_s[h]) * ws_s[h];
    }
    acc += __shfl_xor(acc, 1);
    acc += __shfl_xor(acc, 2);
    acc += __shfl_xor(acc, 4);
    acc += __shfl_xor(acc, 8);
    acc += __shfl_xor(acc, 16);
    acc += __shfl_xor(acc, 32);
    if (l == 0) e_s[w * 8 + tt] = acc;
  }
  __syncthreads();
  if (tid < 64) {
    const float e = e_s[tid];
    float m = e;
    for (int off = 32; off; off >>= 1) m = fmaxf(m, __shfl_xor(m, off));
    const float p = __expf(e - m);
    float sum = p;
    for (int off = 32; off; off >>= 1) sum += __shfl_xor(sum, off);
    const float a = p / sum;
    e_s[tid] = a;
    attn_map[((long)b * 64 + tid) * NS_ + s] = a;
  }
  __syncthreads();
  const int half = tid >> 8, jj = tid & 255;
  float c0 = 0.f, c1 = 0.f;
  const unsigned* bhp = (const unsigned*)(bH + ((long)b * 64 + half * 32) * 512) + jj;
#pragma unroll 8
  for (int t = 0; t < 32; ++t) {
    const float a = e_s[half * 32 + t];
    const unsigned pv = bhp[(long)t * 256];
    c0 += a * bf2f((unsigned short)(pv & 0xffffu));
    c1 += a * bf2f((unsigned short)(pv >> 16));
  }
  if (half) { csum[jj * 2] = c0; csum[jj * 2 + 1] = c1; }
  __syncthreads();
  if (!half) {
    c0 += csum[jj * 2];
    c1 += csum[jj * 2 + 1];
    ((unsigned*)ctx)[(long)b * 256 + jj] = (unsigned)f2bf(c0) | ((unsigned)f2bf(c1) << 16);
  }
}

// ============ GatedBimodal fused: f1/f2/z GEMMs + gating epilogue ============
__global__ __launch_bounds__(256) void gated_fused_k(
    const unsigned short* __restrict__ ctx, const unsigned short* __restrict__ ASb,
    const unsigned short* __restrict__ Wf1b, const unsigned short* __restrict__ Wf2b,
    const unsigned short* __restrict__ Wzb,
    const float* __restrict__ bf1, const float* __restrict__ bf2,
    const float* __restrict__ bz,
    unsigned short* __restrict__ Ichar, float* __restrict__ Char_out, int s) {
  const int tid = threadIdx.x, w = tid >> 6, l = tid & 63, l15 = l & 15, lq = l >> 4;
  const int b0 = blockIdx.y * 64, j0 = blockIdx.x * 64;
  const long arow = b0 + w * 16 + l15;
  f32x4 az[4] = {}, af1[4] = {}, af2[4] = {};
  for (int kt = 0; kt < 1024; kt += 32) {
    const int k = kt + lq * 8;
    bf16x8 a;
    if (kt < 512) a = *(const bf16x8*)(ctx + arow * 512 + k);
    else          a = *(const bf16x8*)(ASb + (arow * NS_ + s) * 512 + (k - 512));
#pragma unroll
    for (int nb = 0; nb < 4; ++nb) {
      const long col = j0 + nb * 16 + l15;
      const bf16x8 wz = *(const bf16x8*)(Wzb + col * 1024 + k);
      az[nb] = __builtin_amdgcn_mfma_f32_16x16x32_bf16(a, wz, az[nb], 0, 0, 0);
      if (kt < 512) {
        const bf16x8 w1 = *(const bf16x8*)(Wf1b + col * 512 + k);
        af1[nb] = __builtin_amdgcn_mfma_f32_16x16x32_bf16(a, w1, af1[nb], 0, 0, 0);
      } else {
        const bf16x8 w2 = *(const bf16x8*)(Wf2b + col * 512 + (k - 512));
        af2[nb] = __builtin_amdgcn_mfma_f32_16x16x32_bf16(a, w2, af2[nb], 0, 0, 0);
      }
    }
  }
#pragma unroll
  for (int nb = 0; nb < 4; ++nb) {
    const int j = j0 + nb * 16 + l15;
    const float B1 = bf1[j], B2 = bf2[j], BZ = bz[j];
#pragma unroll
    for (int r = 0; r < 4; ++r) {
      const long b = b0 + w * 16 + lq * 4 + r;
      const float v1 = tanh_f(af1[nb][r] + B1);
      const float v2 = tanh_f(af2[nb][r] + B2);
      const float z = sigm_f(az[nb][r] + BZ);
      const float I = z * v1 + (1.f - z) * v2;
      Char_out[(b * NS_ + s) * 512 + j] = I;
      Ichar[b * 512 + j] = f2bf(I);
    }
  }
}

// ============ gates GEMM (K=1280) + LSTM epilogue ============
__global__ __launch_bounds__(256) void gates_lstm_k(
    const unsigned short* __restrict__ Ichar, const unsigned short* __restrict__ embb,
    const unsigned short* __restrict__ hrd, const unsigned short* __restrict__ Wihh,
    const float* __restrict__ biasG, float* __restrict__ cbuf,
    float* __restrict__ hid_out, unsigned short* __restrict__ Hall,
    unsigned short* __restrict__ hwr, int s) {
  const int tid = threadIdx.x, w = tid >> 6, l = tid & 63, l15 = l & 15, lq = l >> 4;
  const int b0 = blockIdx.y * 64, j0 = blockIdx.x * 64;
  const long arow = b0 + w * 16 + l15;
  f32x4 acc[4][4] = {};
  for (int kt = 0; kt < 1280; kt += 32) {
    const int k = kt + lq * 8;
    bf16x8 a;
    if (kt < 512)      a = *(const bf16x8*)(Ichar + arow * 512 + k);
    else if (kt < 768) a = *(const bf16x8*)(embb + (arow * NS_ + s) * 256 + (k - 512));
    else               a = *(const bf16x8*)(hrd + arow * 512 + (k - 768));
#pragma unroll
    for (int g = 0; g < 4; ++g)
#pragma unroll
      for (int nb = 0; nb < 4; ++nb) {
        const long wrow = g * 512 + j0 + nb * 16 + l15;
        const bf16x8 wf = *(const bf16x8*)(Wihh + wrow * 1280 + k);
        acc[g][nb] = __builtin_amdgcn_mfma_f32_16x16x32_bf16(a, wf, acc[g][nb], 0, 0, 0);
      }
  }
#pragma unroll
  for (int nb = 0; nb < 4; ++nb) {
    const int j = j0 + nb * 16 + l15;
    const float bi = biasG[j], bff = biasG[512 + j], bg = biasG[1024 + j], bo = biasG[1536 + j];
#pragma unroll
    for (int r = 0; r < 4; ++r) {
      const long b = b0 + w * 16 + lq * 4 + r;
      const float ig = sigm_f(acc[0][nb][r] + bi);
      const float fg = sigm_f(acc[1][nb][r] + bff);
      const float gg = tanh_f(acc[2][nb][r] + bg);
      const float og = sigm_f(acc[3][nb][r] + bo);
      const float c = fg * cbuf[b * 512 + j] + ig * gg;
      cbuf[b * 512 + j] = c;
      const float h = og * tanh_f(c);
      hid_out[(b * NS_ + s) * 512 + j] = h;
      const unsigned short hb = f2bf(h);
      Hall[(b * NS_ + s) * 512 + j] = hb;
      hwr[b * 512 + j] = hb;
    }
  }
}

// ============ prologue helpers ============
__global__ void cvt_f32_bf16_k(const float* __restrict__ in, unsigned short* __restrict__ out, long n) {
  const long i = ((long)blockIdx.x * 256 + threadIdx.x) * 4;
  if (i + 4 <= n) {
    const float4 v = *(const float4*)(in + i);
    ushort4 o;
    o.x = f2bf(v.x); o.y = f2bf(v.y); o.z = f2bf(v.z); o.w = f2bf(v.w);
    *(ushort4*)(out + i) = o;
  }
}

__global__ void embed_k(const float* __restrict__ emb_table, const int* __restrict__ text,
                        unsigned short* __restrict__ out) {
  const int bs = blockIdx.x, j = threadIdx.x;
  const int t = text[bs];
  out[(long)bs * 256 + j] = f2bf(emb_table[(long)t * 256 + j]);
}

// Wihh [2048,1280]: cols 0..767 = W_ih, cols 768..1279 = W_hh
__global__ void pack_Wihh_k(const float* __restrict__ W_ih, const float* __restrict__ W_hh,
                            unsigned short* __restrict__ out) {
  const long idx = (long)blockIdx.x * 256 + threadIdx.x;  // 2048*1280
  const int row = (int)(idx / 1280), c = (int)(idx % 1280);
  const float v = (c < 768) ? W_ih[(long)row * 768 + c] : W_hh[(long)row * 512 + (c - 768)];
  out[idx] = f2bf(v);
}

// Wgen padded to [128,512]
__global__ void pack_Wgen_k(const float* __restrict__ W_gen, unsigned short* __restrict__ out) {
  const long idx = (long)blockIdx.x * 256 + threadIdx.x;  // 128*512
  const int row = (int)(idx >> 9), k = (int)(idx & 511);
  out[idx] = (row < NCLS_) ? f2bf(W_gen[(long)row * 512 + k]) : (unsigned short)0;
}

__global__ void pack_biasG_k(const float* __restrict__ b_ih, const float* __restrict__ b_hh,
                             float* __restrict__ biasG) {
  const int i = blockIdx.x * 256 + threadIdx.x;  // 2048
  biasG[i] = b_ih[i] + b_hh[i];
}

extern "C" void kernel_launch(void* const* d_in, const int* in_sizes, int n_in,
                              void* d_out, int out_size, void* d_ws, size_t ws_size,
                              hipStream_t stream) {
  (void)in_sizes; (void)n_in; (void)out_size; (void)ws_size;
  const float* batch_H  = (const float*)d_in[0];
  const float* AS       = (const float*)d_in[1];
  const int*   text     = (const int*)d_in[2];
  const float* W_i2h    = (const float*)d_in[3];
  const float* W_h2h    = (const float*)d_in[4];
  const float* b_h2h    = (const float*)d_in[5];
  const float* w_score  = (const float*)d_in[6];
  const float* W_ih     = (const float*)d_in[7];
  const float* W_hh     = (const float*)d_in[8];
  const float* b_ih     = (const float*)d_in[9];
  const float* b_hh     = (const float*)d_in[10];
  const float* Wf1      = (const float*)d_in[11];
  const float* bf1      = (const float*)d_in[12];
  const float* Wf2      = (const float*)d_in[13];
  const float* bf2      = (const float*)d_in[14];
  const float* Wz       = (const float*)d_in[15];
  const float* bz       = (const float*)d_in[16];
  const float* W_gen    = (const float*)d_in[17];
  const float* b_gen    = (const float*)d_in[18];
  const float* emb_tab  = (const float*)d_in[19];

  float* out = (float*)d_out;
  float* out_probs = out;                       // [B,NS,NCLS]
  float* out_attn  = out + 1291264;             // [B,T,NS]
  float* out_hid   = out + 2143232;             // [B,NS,H]
  float* out_char  = out + 8958976;             // [B,NS,H]

  char* wsp = (char*)d_ws;
  auto alloc = [&](size_t bytes) { char* p = wsp; wsp += (bytes + 255) & ~(size_t)255; return p; };
  unsigned short* bH    = (unsigned short*)alloc(33554432);  // [B,T,C] bf16
  unsigned short* Hproj = (unsigned short*)alloc(33554432);  // [B,T,H] bf16
  unsigned short* ASb   = (unsigned short*)alloc(13631488);  // [B,NS,H] bf16
  unsigned short* embb  = (unsigned short*)alloc(6815744);   // [B,NS,NEMB] bf16
  unsigned short* Hall  = (unsigned short*)alloc(13631488);  // [B,NS,H] bf16
  unsigned short* Wh2hb = (unsigned short*)alloc(524288);    // [512,512]
  unsigned short* Wf1b  = (unsigned short*)alloc(524288);    // [512,512]
  unsigned short* Wf2b  = (unsigned short*)alloc(524288);    // [512,512]
  unsigned short* Wzb   = (unsigned short*)alloc(1048576);   // [512,1024]
  unsigned short* Wihh  = (unsigned short*)alloc(5242880);   // [2048,1280]
  unsigned short* Wgenb = (unsigned short*)alloc(131072);    // [128,512]
  unsigned short* Wi2hb = (unsigned short*)alloc(524288);    // [512,512]
  float* biasG          = (float*)alloc(8192);               // [2048]
  float* hp             = (float*)alloc(1048576);            // [B,512] f32
  unsigned short* ctx   = (unsigned short*)alloc(524288);    // [B,512] bf16
  unsigned short* Ichar = (unsigned short*)alloc(524288);    // [B,512] bf16
  float* cbuf           = (float*)alloc(1048576);            // [B,512] f32
  unsigned short* hbuf  = (unsigned short*)alloc(1048576);   // 2x [B,512] bf16

  hipMemsetAsync(hbuf, 0, 1048576, stream);
  hipMemsetAsync(cbuf, 0, 1048576, stream);

  // -------- prologue --------
  cvt_f32_bf16_k<<<dim3(16384), dim3(256), 0, stream>>>(batch_H, bH, 16777216);
  cvt_f32_bf16_k<<<dim3(6656), dim3(256), 0, stream>>>(AS, ASb, 6815744);
  cvt_f32_bf16_k<<<dim3(256), dim3(256), 0, stream>>>(W_i2h, Wi2hb, 262144);
  cvt_f32_bf16_k<<<dim3(256), dim3(256), 0, stream>>>(W_h2h, Wh2hb, 262144);
  cvt_f32_bf16_k<<<dim3(256), dim3(256), 0, stream>>>(Wf1, Wf1b, 262144);
  cvt_f32_bf16_k<<<dim3(256), dim3(256), 0, stream>>>(Wf2, Wf2b, 262144);
  cvt_f32_bf16_k<<<dim3(512), dim3(256), 0, stream>>>(Wz, Wzb, 524288);
  embed_k<<<dim3(13312), dim3(256), 0, stream>>>(emb_tab, text, embb);
  pack_Wihh_k<<<dim3(10240), dim3(256), 0, stream>>>(W_ih, W_hh, Wihh);
  pack_Wgen_k<<<dim3(256), dim3(256), 0, stream>>>(W_gen, Wgenb);
  pack_biasG_k<<<dim3(8), dim3(256), 0, stream>>>(b_ih, b_hh, biasG);

  // H_proj = batch_H @ W_i2h^T  (M=32768, N=512, K=512) -> bf16
  gemm_tiled_k<false><<<dim3(4, 256), dim3(256), 0, stream>>>(
      bH, Wi2hb, nullptr, nullptr, Hproj, 512, 512, 512);

  // -------- 26-step scan --------
  for (int s = 0; s < NS_; ++s) {
    unsigned short* hrd = hbuf + (s & 1) * 262144;
    unsigned short* hwr = hbuf + ((s + 1) & 1) * 262144;
    gemm_hp_k<<<dim3(8, 8), dim3(256), 0, stream>>>(hrd, Wh2hb, b_h2h, hp);
    attn_step_k<<<dim3(512), dim3(512), 0, stream>>>(Hproj, bH, hp, w_score, out_attn, ctx, s);
    gated_fused_k<<<dim3(8, 8), dim3(256), 0, stream>>>(
        ctx, ASb, Wf1b, Wf2b, Wzb, bf1, bf2, bz, Ichar, out_char, s);
    gates_lstm_k<<<dim3(8, 8), dim3(256), 0, stream>>>(
        Ichar, embb, hrd, Wihh, biasG, cbuf, out_hid, Hall, hwr, s);
  }

  // probs = Hall @ W_gen^T + b_gen  (M=13312, N=128 padded, K=512, Nvalid=97)
  gemm_tiled_k<true><<<dim3(1, 104), dim3(256), 0, stream>>>(
      Hall, Wgenb, b_gen, out_probs, nullptr, 512, 97, 97);
}

// Round 3
// 2370.898 us; speedup vs baseline: 2.0326x; 2.0326x over previous
//
#include <hip/hip_runtime.h>

#define NS_ 26
#define NCLS_ 97

typedef short bf16x8 __attribute__((ext_vector_type(8)));
typedef float f32x4 __attribute__((ext_vector_type(4)));

__device__ __forceinline__ unsigned short f2bf(float f) {
  union { float f; unsigned u; } v; v.f = f;
  unsigned r = v.u + 0x7fffu + ((v.u >> 16) & 1u);
  return (unsigned short)(r >> 16);
}
__device__ __forceinline__ float bf2f(unsigned short h) {
  union { unsigned u; float f; } v; v.u = ((unsigned)h) << 16;
  return v.f;
}
__device__ __forceinline__ float sigm_f(float x) { return 1.f / (1.f + __expf(-x)); }
__device__ __forceinline__ float tanh_f(float x) { return 1.f - 2.f / (1.f + __expf(2.f * x)); }

__device__ __forceinline__ void gl_lds16(const void* g, void* l) {
  __builtin_amdgcn_global_load_lds(
      (const __attribute__((address_space(1))) unsigned int*)g,
      (__attribute__((address_space(3))) unsigned int*)l, 16, 0, 0);
}

// ============ tiled 128x128 GEMM, BK=64, swizzled LDS, global_load_lds ============
// out[M,N] = A[M,K] @ B[N,K]^T (+bias). M%128==0, K%64==0, B has >= gridDim.x*128 rows.
template <bool OUTF>
__global__ __launch_bounds__(256) void gemm_tiled_k(
    const unsigned short* __restrict__ Ag, const unsigned short* __restrict__ Bg,
    const float* __restrict__ bias, float* __restrict__ outF,
    unsigned short* __restrict__ outB, int K, long ldo, int Nvalid) {
  __shared__ unsigned short As[128 * 64];
  __shared__ unsigned short Bs[128 * 64];
  const int tid = threadIdx.x;
  const int w = tid >> 6, l = tid & 63;
  const int l15 = l & 15, lq = l >> 4;
  const int wm = w >> 1, wn = w & 1;
  const long rowBase = (long)blockIdx.y * 128;
  const long colBase = (long)blockIdx.x * 128;
  const int lrow = l >> 3, ps_st = l & 7;
  f32x4 acc[4][4] = {};
  for (int kt = 0; kt < K; kt += 64) {
#pragma unroll
    for (int i = 0; i < 4; ++i) {
      const int row = i * 32 + w * 8 + lrow;
      const int ls = ps_st ^ (row & 7);
      gl_lds16(Ag + (rowBase + row) * K + kt + ls * 8, As + i * 2048 + w * 512);
      gl_lds16(Bg + (colBase + row) * K + kt + ls * 8, Bs + i * 2048 + w * 512);
    }
    __syncthreads();
#pragma unroll
    for (int kh = 0; kh < 2; ++kh) {
      bf16x8 af[4], bfr[4];
#pragma unroll
      for (int mi = 0; mi < 4; ++mi) {
        const int row = wm * 64 + mi * 16 + l15;
        const int ps = (kh * 4 + lq) ^ (row & 7);
        af[mi] = *(const bf16x8*)(As + row * 64 + ps * 8);
      }
#pragma unroll
      for (int ni = 0; ni < 4; ++ni) {
        const int row = wn * 64 + ni * 16 + l15;
        const int ps = (kh * 4 + lq) ^ (row & 7);
        bfr[ni] = *(const bf16x8*)(Bs + row * 64 + ps * 8);
      }
#pragma unroll
      for (int mi = 0; mi < 4; ++mi)
#pragma unroll
        for (int ni = 0; ni < 4; ++ni)
          acc[mi][ni] = __builtin_amdgcn_mfma_f32_16x16x32_bf16(af[mi], bfr[ni], acc[mi][ni], 0, 0, 0);
    }
    __syncthreads();
  }
#pragma unroll
  for (int mi = 0; mi < 4; ++mi)
#pragma unroll
    for (int ni = 0; ni < 4; ++ni) {
      const long gcol = colBase + wn * 64 + ni * 16 + l15;
      if (gcol >= Nvalid) continue;
      const float bv = bias ? bias[gcol] : 0.f;
#pragma unroll
      for (int r = 0; r < 4; ++r) {
        const long grow = rowBase + wm * 64 + mi * 16 + lq * 4 + r;
        const float v = acc[mi][ni][r] + bv;
        if (OUTF) outF[grow * ldo + gcol] = v;
        else      outB[grow * ldo + gcol] = f2bf(v);
      }
    }
}

// ============ K1: hpgh = h @ [W_h2h | W_hh]^T + [b_h2h | b_ih+b_hh]  (M=512,N=2560,K=512) ============
__global__ __launch_bounds__(256) void gemm_hpgh_k(
    const unsigned short* __restrict__ h, const unsigned short* __restrict__ WA,
    const float* __restrict__ biasA, float* __restrict__ hpgh) {
  const int tid = threadIdx.x, w = tid >> 6, l = tid & 63, l15 = l & 15, lq = l >> 4;
  const long mrow = (long)blockIdx.y * 64 + w * 16 + l15;
  const int nbase = blockIdx.x * 64;
  f32x4 acc[4] = {};
  for (int kt = 0; kt < 512; kt += 64) {
    const int k0 = kt + lq * 8, k1 = k0 + 32;
    const bf16x8 a0 = *(const bf16x8*)(h + mrow * 512 + k0);
    const bf16x8 a1 = *(const bf16x8*)(h + mrow * 512 + k1);
    bf16x8 b0[4], b1[4];
#pragma unroll
    for (int nb = 0; nb < 4; ++nb) {
      const long wr = nbase + nb * 16 + l15;
      b0[nb] = *(const bf16x8*)(WA + wr * 512 + k0);
      b1[nb] = *(const bf16x8*)(WA + wr * 512 + k1);
    }
#pragma unroll
    for (int nb = 0; nb < 4; ++nb) {
      acc[nb] = __builtin_amdgcn_mfma_f32_16x16x32_bf16(a0, b0[nb], acc[nb], 0, 0, 0);
      acc[nb] = __builtin_amdgcn_mfma_f32_16x16x32_bf16(a1, b1[nb], acc[nb], 0, 0, 0);
    }
  }
#pragma unroll
  for (int nb = 0; nb < 4; ++nb) {
    const int colg = nbase + nb * 16 + l15;
    const float bv = biasA[colg];
#pragma unroll
    for (int r = 0; r < 4; ++r) {
      const long rowg = (long)blockIdx.y * 64 + w * 16 + lq * 4 + r;
      hpgh[rowg * 2560 + colg] = acc[nb][r] + bv;
    }
  }
}

// ============ K2: attention step: e -> softmax -> context ============
__global__ __launch_bounds__(512) void attn_step_k(
    const unsigned short* __restrict__ Hproj, const unsigned short* __restrict__ bH,
    const float* __restrict__ hpgh, const float* __restrict__ w_score,
    float* __restrict__ attn_map, unsigned short* __restrict__ ctx, int s) {
  const int b = blockIdx.x, tid = threadIdx.x;
  __shared__ float hp_s[512], ws_s[512], e_s[64], csum[512];
  hp_s[tid] = hpgh[(long)b * 2560 + tid];
  ws_s[tid] = w_score[tid];
  __syncthreads();
  const int w = tid >> 6, l = tid & 63;
  const unsigned short* Hrow = Hproj + ((long)b * 64 + w * 8) * 512 + l * 8;
#pragma unroll
  for (int tt = 0; tt < 8; ++tt) {
    const bf16x8 hv = *(const bf16x8*)(Hrow + tt * 512);
    float acc = 0.f;
#pragma unroll
    for (int j = 0; j < 8; ++j) {
      const int h = l * 8 + j;
      acc += tanh_f(bf2f((unsigned short)hv[j]) + hp_s[h]) * ws_s[h];
    }
    acc += __shfl_xor(acc, 1);
    acc += __shfl_xor(acc, 2);
    acc += __shfl_xor(acc, 4);
    acc += __shfl_xor(acc, 8);
    acc += __shfl_xor(acc, 16);
    acc += __shfl_xor(acc, 32);
    if (l == 0) e_s[w * 8 + tt] = acc;
  }
  __syncthreads();
  if (tid < 64) {
    const float e = e_s[tid];
    float m = e;
    for (int off = 32; off; off >>= 1) m = fmaxf(m, __shfl_xor(m, off));
    const float p = __expf(e - m);
    float sum = p;
    for (int off = 32; off; off >>= 1) sum += __shfl_xor(sum, off);
    const float a = p / sum;
    e_s[tid] = a;
    attn_map[((long)b * 64 + tid) * NS_ + s] = a;
  }
  __syncthreads();
  const int half = tid >> 8, jj = tid & 255;
  float c0 = 0.f, c1 = 0.f;
  const unsigned* bhp = (const unsigned*)(bH + ((long)b * 64 + half * 32) * 512) + jj;
#pragma unroll 8
  for (int t = 0; t < 32; ++t) {
    const float a = e_s[half * 32 + t];
    const unsigned pv = bhp[(long)t * 256];
    c0 += a * bf2f((unsigned short)(pv & 0xffffu));
    c1 += a * bf2f((unsigned short)(pv >> 16));
  }
  if (half) { csum[jj * 2] = c0; csum[jj * 2 + 1] = c1; }
  __syncthreads();
  if (!half) {
    c0 += csum[jj * 2];
    c1 += csum[jj * 2 + 1];
    ((unsigned*)ctx)[(long)b * 256 + jj] = (unsigned)f2bf(c0) | ((unsigned)f2bf(c1) << 16);
  }
}

// ============ K3: gated fused: [f1|z_ctx] = ctx @ Wfz^T, gating with precomputed f2/zseq ============
// grid (8 jtiles, 8 btiles) x 512 thr. Wfz [1024,512]: rows 0..511 Wf1, rows 512..1023 Wz[:, :512].
__global__ __launch_bounds__(512) void gated_fused_k(
    const unsigned short* __restrict__ ctx, const unsigned short* __restrict__ Wfz,
    const unsigned short* __restrict__ FZpre, const float* __restrict__ bf1,
    unsigned short* __restrict__ Ichar, float* __restrict__ Char_out, int s) {
  __shared__ float ls[2 * 64 * 65];
  const int tid = threadIdx.x, w = tid >> 6, l = tid & 63, l15 = l & 15, lq = l >> 4;
  const int b0 = blockIdx.y * 64, j0 = blockIdx.x * 64;
  const int mi2 = w & 1, nq = w >> 1;
  f32x4 acc[2][2] = {};
  for (int kt = 0; kt < 512; kt += 64) {
    const int k0 = kt + lq * 8, k1 = k0 + 32;
    bf16x8 a0[2], a1[2], bb0[2], bb1[2];
#pragma unroll
    for (int mi = 0; mi < 2; ++mi) {
      const long row = b0 + mi2 * 32 + mi * 16 + l15;
      a0[mi] = *(const bf16x8*)(ctx + row * 512 + k0);
      a1[mi] = *(const bf16x8*)(ctx + row * 512 + k1);
    }
#pragma unroll
    for (int ni = 0; ni < 2; ++ni) {
      const int wl = nq * 32 + ni * 16 + l15;
      const long gw = (wl < 64) ? (j0 + wl) : (512 + j0 + wl - 64);
      bb0[ni] = *(const bf16x8*)(Wfz + gw * 512 + k0);
      bb1[ni] = *(const bf16x8*)(Wfz + gw * 512 + k1);
    }
#pragma unroll
    for (int mi = 0; mi < 2; ++mi)
#pragma unroll
      for (int ni = 0; ni < 2; ++ni) {
        acc[mi][ni] = __builtin_amdgcn_mfma_f32_16x16x32_bf16(a0[mi], bb0[ni], acc[mi][ni], 0, 0, 0);
        acc[mi][ni] = __builtin_amdgcn_mfma_f32_16x16x32_bf16(a1[mi], bb1[ni], acc[mi][ni], 0, 0, 0);
      }
  }
  float* dst = ls + (nq >> 1) * (64 * 65);
#pragma unroll
  for (int mi = 0; mi < 2; ++mi)
#pragma unroll
    for (int ni = 0; ni < 2; ++ni)
#pragma unroll
      for (int r = 0; r < 4; ++r) {
        const int rl = mi2 * 32 + mi * 16 + lq * 4 + r;
        const int cl = (nq & 1) * 32 + ni * 16 + l15;
        dst[rl * 65 + cl] = acc[mi][ni][r];
      }
  __syncthreads();
#pragma unroll
  for (int i = 0; i < 8; ++i) {
    const int e = tid + i * 512;
    const int r = e >> 6, c = e & 63;
    const long b = b0 + r;
    const int j = j0 + c;
    const float f1 = tanh_f(ls[r * 65 + c] + bf1[j]);
    const float zc = ls[64 * 65 + r * 65 + c];
    const long prerow = (b * NS_ + s) * 1024;
    const float f2 = tanh_f(bf2f(FZpre[prerow + j]));
    const float z = sigm_f(zc + bf2f(FZpre[prerow + 512 + j]));
    const float I = z * f1 + (1.f - z) * f2;
    Char_out[(b * NS_ + s) * 512 + j] = I;
    Ichar[b * 512 + j] = f2bf(I);
  }
}

// ============ K4: gates = [I_char|emb] @ W_ih^T + gh, LSTM epilogue ============
// grid (8 jtiles, 16 btiles) x 512 thr. wave = (gate g = w&3, row-half mi = w>>2).
__global__ __launch_bounds__(512) void gates_lstm_k(
    const unsigned short* __restrict__ Ichar, const unsigned short* __restrict__ embb,
    const unsigned short* __restrict__ WihE, const float* __restrict__ hpgh,
    float* __restrict__ cbuf, float* __restrict__ hid_out,
    unsigned short* __restrict__ hwr, int s) {
  __shared__ float gs[4 * 32 * 65];
  const int tid = threadIdx.x, w = tid >> 6, l = tid & 63, l15 = l & 15, lq = l >> 4;
  const int b0 = blockIdx.y * 32, j0 = blockIdx.x * 64;
  const int g = w & 3, mi = w >> 2;
  const long arow = b0 + mi * 16 + l15;
  f32x4 acc[4] = {};
  for (int kt = 0; kt < 768; kt += 64) {
    const int k0 = kt + lq * 8, k1 = k0 + 32;
    bf16x8 a0, a1, b0r[4], b1r[4];
    a0 = (k0 < 512) ? *(const bf16x8*)(Ichar + arow * 512 + k0)
                    : *(const bf16x8*)(embb + (arow * NS_ + s) * 256 + (k0 - 512));
    a1 = (k1 < 512) ? *(const bf16x8*)(Ichar + arow * 512 + k1)
                    : *(const bf16x8*)(embb + (arow * NS_ + s) * 256 + (k1 - 512));
#pragma unroll
    for (int ni = 0; ni < 4; ++ni) {
      const long wrow = g * 512 + j0 + ni * 16 + l15;
      b0r[ni] = *(const bf16x8*)(WihE + wrow * 768 + k0);
      b1r[ni] = *(const bf16x8*)(WihE + wrow * 768 + k1);
    }
#pragma unroll
    for (int ni = 0; ni < 4; ++ni) {
      acc[ni] = __builtin_amdgcn_mfma_f32_16x16x32_bf16(a0, b0r[ni], acc[ni], 0, 0, 0);
      acc[ni] = __builtin_amdgcn_mfma_f32_16x16x32_bf16(a1, b1r[ni], acc[ni], 0, 0, 0);
    }
  }
#pragma unroll
  for (int ni = 0; ni < 4; ++ni)
#pragma unroll
    for (int r = 0; r < 4; ++r) {
      const int rl = mi * 16 + lq * 4 + r;
      const int cl = ni * 16 + l15;
      gs[(g * 32 + rl) * 65 + cl] = acc[ni][r];
    }
  __syncthreads();
#pragma unroll
  for (int i = 0; i < 4; ++i) {
    const int e = tid + i * 512;
    const int r = e >> 6, c = e & 63;
    const long b = b0 + r;
    const int j = j0 + c;
    const float* ggh = hpgh + b * 2560 + 512;
    const float ig = sigm_f(gs[(0 * 32 + r) * 65 + c] + ggh[j]);
    const float fg = sigm_f(gs[(1 * 32 + r) * 65 + c] + ggh[512 + j]);
    const float gg = tanh_f(gs[(2 * 32 + r) * 65 + c] + ggh[1024 + j]);
    const float og = sigm_f(gs[(3 * 32 + r) * 65 + c] + ggh[1536 + j]);
    const float cn = fg * cbuf[b * 512 + j] + ig * gg;
    cbuf[b * 512 + j] = cn;
    const float h = og * tanh_f(cn);
    hid_out[(b * NS_ + s) * 512 + j] = h;
    hwr[b * 512 + j] = f2bf(h);
  }
}

// ============ final probs GEMM: out_hid(f32) @ W_gen^T + b_gen ============
__global__ __launch_bounds__(256) void probs_k(
    const float* __restrict__ A, const unsigned short* __restrict__ Wg,
    const float* __restrict__ bias, float* __restrict__ outp) {
  const int tid = threadIdx.x, w = tid >> 6, l = tid & 63, l15 = l & 15, lq = l >> 4;
  const long mrow = (long)blockIdx.y * 64 + w * 16 + l15;
  const int nbase = blockIdx.x * 64;
  f32x4 acc[4] = {};
  for (int kt = 0; kt < 512; kt += 32) {
    const int k = kt + lq * 8;
    const float4 av0 = *(const float4*)(A + mrow * 512 + k);
    const float4 av1 = *(const float4*)(A + mrow * 512 + k + 4);
    bf16x8 a;
    a[0] = (short)f2bf(av0.x); a[1] = (short)f2bf(av0.y);
    a[2] = (short)f2bf(av0.z); a[3] = (short)f2bf(av0.w);
    a[4] = (short)f2bf(av1.x); a[5] = (short)f2bf(av1.y);
    a[6] = (short)f2bf(av1.z); a[7] = (short)f2bf(av1.w);
#pragma unroll
    for (int nb = 0; nb < 4; ++nb) {
      const bf16x8 b = *(const bf16x8*)(Wg + (long)(nbase + nb * 16 + l15) * 512 + k);
      acc[nb] = __builtin_amdgcn_mfma_f32_16x16x32_bf16(a, b, acc[nb], 0, 0, 0);
    }
  }
#pragma unroll
  for (int nb = 0; nb < 4; ++nb) {
    const int colg = nbase + nb * 16 + l15;
    if (colg >= NCLS_) continue;
    const float bv = bias[colg];
#pragma unroll
    for (int r = 0; r < 4; ++r) {
      const long rowg = (long)blockIdx.y * 64 + w * 16 + lq * 4 + r;
      outp[rowg * NCLS_ + colg] = acc[nb][r] + bv;
    }
  }
}

// ============ prologue helpers ============
__global__ void cvt_f32_bf16_k(const float* __restrict__ in, unsigned short* __restrict__ out, long n) {
  const long i = ((long)blockIdx.x * 256 + threadIdx.x) * 4;
  if (i + 4 <= n) {
    const float4 v = *(const float4*)(in + i);
    ushort4 o;
    o.x = f2bf(v.x); o.y = f2bf(v.y); o.z = f2bf(v.z); o.w = f2bf(v.w);
    *(ushort4*)(out + i) = o;
  }
}

__global__ void embed_k(const float* __restrict__ emb_table, const int* __restrict__ text,
                        unsigned short* __restrict__ out) {
  const int bs = blockIdx.x, j = threadIdx.x;
  const int t = text[bs];
  out[(long)bs * 256 + j] = f2bf(emb_table[(long)t * 256 + j]);
}

// WA [2560,512]: rows 0..511 W_h2h; rows 512..2559 W_hh
__global__ void pack_WA_k(const float* __restrict__ W_h2h, const float* __restrict__ W_hh,
                          unsigned short* __restrict__ out) {
  const long idx = (long)blockIdx.x * 256 + threadIdx.x;
  const int row = (int)(idx >> 9), k = (int)(idx & 511);
  const float v = (row < 512) ? W_h2h[(long)row * 512 + k] : W_hh[(long)(row - 512) * 512 + k];
  out[idx] = f2bf(v);
}

// [1024,512]: rows 0..511 Wf; rows 512..1023 Wz[:, zoff..zoff+512)
__global__ void pack_wfz_k(const float* __restrict__ Wf, const float* __restrict__ Wz, int zoff,
                           unsigned short* __restrict__ out) {
  const long idx = (long)blockIdx.x * 256 + threadIdx.x;
  const int row = (int)(idx >> 9), k = (int)(idx & 511);
  const float v = (row < 512) ? Wf[(long)row * 512 + k]
                              : Wz[(long)(row - 512) * 1024 + zoff + k];
  out[idx] = f2bf(v);
}

__global__ void pack_Wgen_k(const float* __restrict__ W_gen, unsigned short* __restrict__ out) {
  const long idx = (long)blockIdx.x * 256 + threadIdx.x;  // 128*512
  const int row = (int)(idx >> 9), k = (int)(idx & 511);
  out[idx] = (row < NCLS_) ? f2bf(W_gen[(long)row * 512 + k]) : (unsigned short)0;
}

// biasA [2560] = [b_h2h | b_ih+b_hh]; biasFZ [1024] = [bf2 | bz]
__global__ void pack_bias_k(const float* __restrict__ b_h2h, const float* __restrict__ b_ih,
                            const float* __restrict__ b_hh, const float* __restrict__ bf2,
                            const float* __restrict__ bz,
                            float* __restrict__ biasA, float* __restrict__ biasFZ) {
  const int i = blockIdx.x * 256 + threadIdx.x;  // 3584
  if (i < 2560) {
    biasA[i] = (i < 512) ? b_h2h[i] : (b_ih[i - 512] + b_hh[i - 512]);
  } else {
    const int j = i - 2560;
    biasFZ[j] = (j < 512) ? bf2[j] : bz[j - 512];
  }
}

extern "C" void kernel_launch(void* const* d_in, const int* in_sizes, int n_in,
                              void* d_out, int out_size, void* d_ws, size_t ws_size,
                              hipStream_t stream) {
  (void)in_sizes; (void)n_in; (void)out_size; (void)ws_size;
  const float* batch_H  = (const float*)d_in[0];
  const float* AS       = (const float*)d_in[1];
  const int*   text     = (const int*)d_in[2];
  const float* W_i2h    = (const float*)d_in[3];
  const float* W_h2h    = (const float*)d_in[4];
  const float* b_h2h    = (const float*)d_in[5];
  const float* w_score  = (const float*)d_in[6];
  const float* W_ih     = (const float*)d_in[7];
  const float* W_hh     = (const float*)d_in[8];
  const float* b_ih     = (const float*)d_in[9];
  const float* b_hh     = (const float*)d_in[10];
  const float* Wf1      = (const float*)d_in[11];
  const float* bf1      = (const float*)d_in[12];
  const float* Wf2      = (const float*)d_in[13];
  const float* bf2      = (const float*)d_in[14];
  const float* Wz       = (const float*)d_in[15];
  const float* bz       = (const float*)d_in[16];
  const float* W_gen    = (const float*)d_in[17];
  const float* b_gen    = (const float*)d_in[18];
  const float* emb_tab  = (const float*)d_in[19];

  float* out = (float*)d_out;
  float* out_probs = out;                       // [B,NS,NCLS]
  float* out_attn  = out + 1291264;             // [B,T,NS]
  float* out_hid   = out + 2143232;             // [B,NS,H]
  float* out_char  = out + 8958976;             // [B,NS,H]

  char* wsp = (char*)d_ws;
  auto alloc = [&](size_t bytes) { char* p = wsp; wsp += (bytes + 255) & ~(size_t)255; return p; };
  unsigned short* bH    = (unsigned short*)alloc(33554432);  // [B,T,C] bf16
  unsigned short* Hproj = (unsigned short*)alloc(33554432);  // [B,T,H] bf16
  unsigned short* ASb   = (unsigned short*)alloc(13631488);  // [B*NS,512] bf16 (prologue only)
  unsigned short* embb  = (unsigned short*)alloc(6815744);   // [B,NS,NEMB] bf16
  unsigned short* FZpre = (unsigned short*)alloc(27262976);  // [B*NS,1024] bf16: [f2lin | zseqlin+bz]
  unsigned short* WA    = (unsigned short*)alloc(2621440);   // [2560,512]
  unsigned short* Wfz   = (unsigned short*)alloc(1048576);   // [1024,512]  (Wf1 | Wz-left)
  unsigned short* Wfz2  = (unsigned short*)alloc(1048576);   // [1024,512]  (Wf2 | Wz-right)
  unsigned short* WihE  = (unsigned short*)alloc(3145728);   // [2048,768]
  unsigned short* Wgenb = (unsigned short*)alloc(131072);    // [128,512]
  unsigned short* Wi2hb = (unsigned short*)alloc(524288);    // [512,512]
  float* biasA          = (float*)alloc(10240);              // [2560]
  float* biasFZ         = (float*)alloc(4096);               // [1024]
  // ---- aliased into ASb (dead after FZpre GEMM) ----
  char* ab = (char*)ASb;
  float* hpgh           = (float*)(ab);                      // [512,2560] f32 (5242880)
  unsigned short* ctx   = (unsigned short*)(ab + 5242880);   // [B,512] bf16 (524288)
  unsigned short* Ichar = (unsigned short*)(ab + 5767168);   // [B,512] bf16 (524288)
  float* cbuf           = (float*)(ab + 6291456);            // [B,512] f32 (1048576)
  unsigned short* hbuf  = (unsigned short*)(ab + 7340032);   // 2x [B,512] bf16 (1048576)

  // -------- prologue --------
  cvt_f32_bf16_k<<<dim3(16384), dim3(256), 0, stream>>>(batch_H, bH, 16777216);
  cvt_f32_bf16_k<<<dim3(6656), dim3(256), 0, stream>>>(AS, ASb, 6815744);
  cvt_f32_bf16_k<<<dim3(256), dim3(256), 0, stream>>>(W_i2h, Wi2hb, 262144);
  cvt_f32_bf16_k<<<dim3(1536), dim3(256), 0, stream>>>(W_ih, WihE, 1572864);
  embed_k<<<dim3(13312), dim3(256), 0, stream>>>(emb_tab, text, embb);
  pack_WA_k<<<dim3(5120), dim3(256), 0, stream>>>(W_h2h, W_hh, WA);
  pack_wfz_k<<<dim3(2048), dim3(256), 0, stream>>>(Wf1, Wz, 0, Wfz);
  pack_wfz_k<<<dim3(2048), dim3(256), 0, stream>>>(Wf2, Wz, 512, Wfz2);
  pack_Wgen_k<<<dim3(256), dim3(256), 0, stream>>>(W_gen, Wgenb);
  pack_bias_k<<<dim3(14), dim3(256), 0, stream>>>(b_h2h, b_ih, b_hh, bf2, bz, biasA, biasFZ);

  // H_proj = batch_H @ W_i2h^T  (M=32768, N=512, K=512) -> bf16
  gemm_tiled_k<false><<<dim3(4, 256), dim3(256), 0, stream>>>(
      bH, Wi2hb, nullptr, nullptr, Hproj, 512, 512, 512);

  // FZpre = AS @ [Wf2 | Wz-right]^T + [bf2 | bz]  (M=13312, N=1024, K=512) -> bf16
  gemm_tiled_k<false><<<dim3(8, 104), dim3(256), 0, stream>>>(
      ASb, Wfz2, biasFZ, nullptr, FZpre, 512, 1024, 1024);

  // now ASb region is dead -> init aliased state buffers
  hipMemsetAsync(cbuf, 0, 1048576, stream);
  hipMemsetAsync(hbuf, 0, 1048576, stream);

  // -------- 26-step scan --------
  for (int s = 0; s < NS_; ++s) {
    unsigned short* hrd = hbuf + (s & 1) * 262144;
    unsigned short* hwr = hbuf + ((s + 1) & 1) * 262144;
    gemm_hpgh_k<<<dim3(40, 8), dim3(256), 0, stream>>>(hrd, WA, biasA, hpgh);
    attn_step_k<<<dim3(512), dim3(512), 0, stream>>>(Hproj, bH, hpgh, w_score, out_attn, ctx, s);
    gated_fused_k<<<dim3(8, 8), dim3(512), 0, stream>>>(
        ctx, Wfz, FZpre, bf1, Ichar, out_char, s);
    gates_lstm_k<<<dim3(8, 16), dim3(512), 0, stream>>>(
        Ichar, embb, WihE, hpgh, cbuf, out_hid, hwr, s);
  }

  // probs = out_hid @ W_gen^T + b_gen  (M=13312, N=128 padded, K=512, Nvalid=97)
  probs_k<<<dim3(2, 208), dim3(256), 0, stream>>>(out_hid, Wgenb, b_gen, out_probs);
}